// Round 8
// baseline (1037.287 us; speedup 1.0000x reference)
//
#include <hip/hip_runtime.h>
#include <hip/hip_bf16.h>
#include <math.h>

#define N_NODES 50000
#define N_EDGES 800000
#define FDIM 128
#define HIST_BLOCKS 3125   // 800000/256 exactly
#define XW_BLOCKS 391      // ceil(50000/128): 4 waves/block, 32 rows/wave
#define NB2 1792           // mega2 grid: 7 blocks/CU * 256 CUs (capacity 8)
#define SCAN_BLOCKS 196    // ceil(50000/256)

typedef unsigned int uint32;
typedef __attribute__((ext_vector_type(8))) __bf16 bf16x8;
typedef __attribute__((ext_vector_type(8))) short short8;
typedef __attribute__((ext_vector_type(16))) float f32x16;

// sync[] ints: [0..3] mega2 barrier counters; [8..8+196) block sums;
//              [208..208+196) scanned exclusive bases
#define SUMS 8
#define SCANNED 208

// round-to-nearest-even fp32 -> bf16 bits (finite inputs)
__device__ inline unsigned short f2bf(float f) {
  unsigned int u = __float_as_uint(f);
  unsigned int r = u + 0x7fffu + ((u >> 16) & 1u);
  return (unsigned short)(r >> 16);
}

// ---------------------------------------------------------------------------
// D1: GRU-evolve W -> bf16 frag-blocked Wb in GLOBAL memory, + zero cnt/sync.
// Wb[((k>>3)<<7 | n)<<3 | (k&7)] = bf16(W[k][n]); a B-fragment (8 consecutive
// k, fixed n) is then one 16-B global load, L1-resident for the xw waves.
// One block per W row k=bid; 256 threads.
// ---------------------------------------------------------------------------
__global__ __launch_bounds__(256) void evolve_kernel(
    const float* __restrict__ W0, const float* __restrict__ Wih,
    const float* __restrict__ Whh, const float* __restrict__ bih,
    const float* __restrict__ bhh, unsigned short* __restrict__ Wb,
    int* __restrict__ cnt, int* __restrict__ sync) {
  int bid = blockIdx.x;  // 0..127 = W row (contraction index k)
  int t = threadIdx.x;
  // fused init: zero cnt[0..N_NODES) and sync counters
  int gid = bid * 256 + t;  // 0..32767
  for (int j = gid; j < N_NODES; j += 128 * 256) cnt[j] = 0;
  if (gid < 8) sync[gid] = 0;

  __shared__ float w0s[FDIM];
  __shared__ float gis[3 * FDIM];
  __shared__ float ghs[3 * FDIM];
  if (t < FDIM) w0s[t] = W0[bid * FDIM + t];
  __syncthreads();
  for (int jj = t; jj < 3 * FDIM; jj += 256) {
    float gi = bih[jj], gh = bhh[jj];
    const float4* wih4 = (const float4*)(Wih + jj * FDIM);
    const float4* whh4 = (const float4*)(Whh + jj * FDIM);
#pragma unroll 8
    for (int k = 0; k < FDIM / 4; k++) {
      float4 a = wih4[k];
      float4 b = whh4[k];
      float w0a = w0s[4 * k], w0b = w0s[4 * k + 1];
      float w0c = w0s[4 * k + 2], w0d = w0s[4 * k + 3];
      gi += a.x * w0a + a.y * w0b + a.z * w0c + a.w * w0d;
      gh += b.x * w0a + b.y * w0b + b.z * w0c + b.w * w0d;
    }
    gis[jj] = gi;
    ghs[jj] = gh;
  }
  __syncthreads();
  if (t < FDIM) {
    float r = 1.0f / (1.0f + expf(-(gis[t] + ghs[t])));
    float z = 1.0f / (1.0f + expf(-(gis[t + FDIM] + ghs[t + FDIM])));
    float nn = tanhf(gis[t + 2 * FDIM] + r * ghs[t + 2 * FDIM]);
    float w = (1.0f - z) * nn + z * w0s[t];
    Wb[((((bid >> 3) << 7) | t) << 3) | (bid & 7)] = f2bf(w);
  }
}

// ---------------------------------------------------------------------------
// D2 (fused, no LDS): blocks [0,HIST_BLOCKS) rank histogram (1 atomic/edge,
// starts immediately); blocks [HIST_BLOCKS..) MFMA y = bf16(x @ W) with
// B-frags read straight from global Wb (L1-hot 32 KB).
// ---------------------------------------------------------------------------
__global__ void histxw_kernel(const int* __restrict__ ei,
                              int* __restrict__ cnt, int* __restrict__ rank,
                              const float* __restrict__ x,
                              const unsigned short* __restrict__ Wb,
                              unsigned short* __restrict__ y, int n) {
  int t = threadIdx.x;
  int bid = blockIdx.x;
  if (bid < HIST_BLOCKS) {
    // ---- hist path: 3125*256 == 800000 exactly ----
    int idx = bid * 256 + t;
    int dst = ei[N_EDGES + idx];
    rank[idx] = atomicAdd(&cnt[dst], 1);
    return;
  }
  // ---- xw path: one wave per 32-row tile, 32x32x16 bf16 MFMA ----
  int lane = t & 63;
  int wid = (bid - HIST_BLOCKS) * 4 + (t >> 6);
  int tr = wid * 32;  // tile row base
  if (tr >= n) return;
  int m = lane & 31;   // A row / D col within tile
  int q2 = lane >> 5;  // half-wave: k-offset selector

  int row = tr + m;
  if (row >= n) row = n - 1;  // tail clamp (stores are guarded)
  const float* xr = x + (size_t)row * FDIM;

  bf16x8 a[8];
#pragma unroll
  for (int kc = 0; kc < 8; kc++) {
    int k0 = kc * 16 + q2 * 8;
    float4 p = *(const float4*)(xr + k0);
    float4 q = *(const float4*)(xr + k0 + 4);
    short8 s;
    s[0] = (short)f2bf(p.x); s[1] = (short)f2bf(p.y);
    s[2] = (short)f2bf(p.z); s[3] = (short)f2bf(p.w);
    s[4] = (short)f2bf(q.x); s[5] = (short)f2bf(q.y);
    s[6] = (short)f2bf(q.z); s[7] = (short)f2bf(q.w);
    a[kc] = __builtin_bit_cast(bf16x8, s);
  }

  f32x16 acc[4];
#pragma unroll
  for (int ct = 0; ct < 4; ct++) {
#pragma unroll
    for (int r = 0; r < 16; r++) acc[ct][r] = 0.0f;
  }
#pragma unroll
  for (int ct = 0; ct < 4; ct++) {
    int nn = ct * 32 + m;
#pragma unroll
    for (int kc = 0; kc < 8; kc++) {
      int kg = kc * 2 + q2;
      bf16x8 b = __builtin_bit_cast(
          bf16x8, *(const short8*)(Wb + (((kg << 7) + nn) << 3)));
      acc[ct] = __builtin_amdgcn_mfma_f32_32x32x16_bf16(a[kc], b, acc[ct], 0,
                                                        0, 0);
    }
  }

  // D layout: col = lane&31, row = (reg&3) + 8*(reg>>2) + 4*(lane>>5)
#pragma unroll
  for (int r = 0; r < 16; r++) {
    int rl = (r & 3) + ((r >> 2) << 3) + (q2 << 2);
    int rg = tr + rl;
    if (rg < n) {
#pragma unroll
      for (int ct = 0; ct < 4; ct++) {
        y[(size_t)rg * FDIM + ct * 32 + m] = f2bf(acc[ct][r]);
      }
    }
  }
}

// ---------------------------------------------------------------------------
// mega2 grid barrier: NB2 co-resident blocks, release/acquire counter.
// ---------------------------------------------------------------------------
__device__ inline void grid_bar(int* ctr, int t) {
  __syncthreads();
  if (t == 0) {
    __hip_atomic_fetch_add(ctr, 1, __ATOMIC_ACQ_REL, __HIP_MEMORY_SCOPE_AGENT);
    while (__hip_atomic_load(ctr, __ATOMIC_ACQUIRE,
                             __HIP_MEMORY_SCOPE_AGENT) < NB2) {
      __builtin_amdgcn_s_sleep(2);
    }
  }
  __syncthreads();
}

// ---------------------------------------------------------------------------
// D3 mega2 (NB2=1792 blocks x 256, 7/CU <= capacity 8 -> co-resident):
//  P1 blocks 0..195: local scan of cnt -> lexcl, block sums     | bar
//  P2 block 0: scan 196 partials -> scanned bases, offs[n]      | bar
//  P3 all: write offs; scatter edges to CSR (edge-parallel)     | bar
//  P4 node-parallel: deg from CSR -> dinv                       | bar
//  P5 node-parallel: csr_w <- w * dinv[src] * dinv[dst]
// ---------------------------------------------------------------------------
__global__ __launch_bounds__(256, 8) void mega2_kernel(
    const int* __restrict__ ei, const float* __restrict__ ew,
    const int* __restrict__ cnt, const int* __restrict__ rank,
    int* __restrict__ sync, int* __restrict__ lexcl, int* __restrict__ offs,
    int2* csr, float* __restrict__ dinv, int n) {
  __shared__ int tmp[256];
  int t = threadIdx.x, bid = blockIdx.x;
  const int STRIDE = NB2 * 256;  // 458752
  int idx = bid * 256 + t;

  // P1: local exclusive scan of cnt (blocks 0..195)
  if (bid < SCAN_BLOCKS) {
    int v = (idx < n) ? cnt[idx] : 0;
    tmp[t] = v;
    __syncthreads();
#pragma unroll
    for (int off = 1; off < 256; off <<= 1) {
      int u = (t >= off) ? tmp[t - off] : 0;
      __syncthreads();
      tmp[t] += u;
      __syncthreads();
    }
    if (idx < n) lexcl[idx] = tmp[t] - v;
    if (t == 255) sync[SUMS + bid] = tmp[255];
  }
  grid_bar(&sync[0], t);

  // P2: block 0 scans the 196 partials
  if (bid == 0) {
    int pv = (t < SCAN_BLOCKS) ? sync[SUMS + t] : 0;
    tmp[t] = pv;
    __syncthreads();
#pragma unroll
    for (int off = 1; off < 256; off <<= 1) {
      int u = (t >= off) ? tmp[t - off] : 0;
      __syncthreads();
      tmp[t] += u;
      __syncthreads();
    }
    if (t < SCAN_BLOCKS) sync[SCANNED + t] = tmp[t] - pv;
    if (t == SCAN_BLOCKS - 1) offs[n] = tmp[t];  // = N_EDGES
  }
  grid_bar(&sync[1], t);

  // P3: offs + edge-parallel scatter (<=2 edges/thread)
  if (idx < n) offs[idx] = sync[SCANNED + (idx >> 8)] + lexcl[idx];
  for (int j = idx; j < N_EDGES; j += STRIDE) {
    int src = ei[j];
    int dst = ei[N_EDGES + j];
    int pos = sync[SCANNED + (dst >> 8)] + lexcl[dst] + rank[j];
    csr[pos] = make_int2(src, __float_as_int(ew[j]));
  }
  grid_bar(&sync[2], t);

  // P4: deg -> dinv (node-parallel)
  if (idx < n) {
    int b = offs[idx], e = offs[idx + 1];
    float d = 1.0f;
    for (int j = b; j < e; j++) d += __int_as_float(csr[j].y);
    dinv[idx] = (d > 0.0f) ? rsqrtf(d) : 0.0f;
  }
  grid_bar(&sync[3], t);

  // P5: full-norm fixup (node-parallel)
  if (idx < n) {
    float dd = dinv[idx];
    int b = offs[idx], e = offs[idx + 1];
    for (int j = b; j < e; j++) {
      int2 c = csr[j];
      csr[j].y = __float_as_int(__int_as_float(c.y) * dinv[c.x] * dd);
    }
  }
}

// ---------------------------------------------------------------------------
// D4: per-node gather (bf16 y rows) + tanh + w_lin dot + bias.
// h[dst] = tanh( dinv_d^2 * y[dst] + sum_e wnorm_e * y[src_e] )
// ---------------------------------------------------------------------------
__global__ __launch_bounds__(256) void gather_kernel(
    const uint32* __restrict__ yb, const int* __restrict__ offs,
    const int2* __restrict__ csr, const float* __restrict__ dinv,
    const float* __restrict__ wl, const float* __restrict__ bl,
    float* __restrict__ out, int n) {
  int wid = (int)((blockIdx.x * (size_t)blockDim.x + threadIdx.x) >> 6);
  int lane = threadIdx.x & 63;
  if (wid >= n) return;
  float di = dinv[wid];
  float sn = di * di;  // self-loop norm
  uint32 uv = yb[(size_t)wid * 64 + lane];
  float ax = sn * __uint_as_float(uv << 16);
  float ay = sn * __uint_as_float(uv & 0xffff0000u);
  int beg = offs[wid], end = offs[wid + 1];
  int e = beg;
  for (; e + 8 <= end; e += 8) {
    int2 c[8];
    uint32 u[8];
#pragma unroll
    for (int q = 0; q < 8; q++) c[q] = csr[e + q];
#pragma unroll
    for (int q = 0; q < 8; q++) u[q] = yb[(size_t)c[q].x * 64 + lane];
#pragma unroll
    for (int q = 0; q < 8; q++) {
      float wn = __int_as_float(c[q].y);
      ax += wn * __uint_as_float(u[q] << 16);
      ay += wn * __uint_as_float(u[q] & 0xffff0000u);
    }
  }
  for (; e < end; e++) {
    int2 c = csr[e];
    uint32 u = yb[(size_t)c.x * 64 + lane];
    float wn = __int_as_float(c.y);
    ax += wn * __uint_as_float(u << 16);
    ay += wn * __uint_as_float(u & 0xffff0000u);
  }
  float2 wv = ((const float2*)wl)[lane];
  float p = tanhf(ax) * wv.x + tanhf(ay) * wv.y;
#pragma unroll
  for (int o = 32; o > 0; o >>= 1) p += __shfl_down(p, o, 64);
  if (lane == 0) out[wid] = p + bl[0];
}

// ---------------------------------------------------------------------------
extern "C" void kernel_launch(void* const* d_in, const int* in_sizes, int n_in,
                              void* d_out, int out_size, void* d_ws,
                              size_t ws_size, hipStream_t stream) {
  const float* x = (const float*)d_in[0];     // (N,128)
  const int* ei = (const int*)d_in[1];        // (2,E)
  const float* ew = (const float*)d_in[2];    // (E,)
  const float* W0 = (const float*)d_in[3];    // (128,128)
  const float* Wih = (const float*)d_in[4];   // (384,128)
  const float* Whh = (const float*)d_in[5];   // (384,128)
  const float* bih = (const float*)d_in[6];   // (384,)
  const float* bhh = (const float*)d_in[7];   // (384,)
  const float* wl = (const float*)d_in[8];    // (1,128)
  const float* bl = (const float*)d_in[9];    // (1,)
  float* out = (float*)d_out;                 // (N,1)

  // Workspace layout (16B-aligned)
  unsigned short* Wb = (unsigned short*)d_ws;            // 16384 bf16 (32 KB)
  unsigned short* y = Wb + 16384;                        // N*128 bf16
  float* dinv = (float*)(y + (size_t)N_NODES * FDIM);    // 50000 f
  int* cnt = (int*)(dinv + N_NODES);                     // 50000 i
  int* sync = cnt + N_NODES;                             // 512 i
  int* rank = sync + 512;                                // 800000 i
  int* lexcl = rank + N_EDGES;                           // 50000 i
  int* offs = lexcl + N_NODES;                           // 50008 i (padded)
  int2* csr = (int2*)(offs + 50008);                     // 800000 int2

  // D1: evolve W -> bf16 frag-blocked Wb; zero cnt + sync
  evolve_kernel<<<FDIM, 256, 0, stream>>>(W0, Wih, Whh, bih, bhh, Wb, cnt,
                                          sync);
  // D2: rank histogram (blocks 0..3124) + xw-MFMA (blocks 3125..3515)
  histxw_kernel<<<HIST_BLOCKS + XW_BLOCKS, 256, 0, stream>>>(ei, cnt, rank, x,
                                                             Wb, y, N_NODES);
  // D3: scan + scatter + deg/dinv + norm fixup (1792 co-resident blocks)
  mega2_kernel<<<NB2, 256, 0, stream>>>(ei, ew, cnt, rank, sync, lexcl, offs,
                                        csr, dinv, N_NODES);
  // D4: fused gather + tanh + linear
  gather_kernel<<<(N_NODES * 64) / 256, 256, 0, stream>>>(
      (const uint32*)y, offs, csr, dinv, wl, bl, out, N_NODES);
}

// Round 9
// 880.905 us; speedup vs baseline: 1.1775x; 1.1775x over previous
//
#include <hip/hip_runtime.h>
#include <hip/hip_bf16.h>
#include <math.h>

#define N_NODES 50000
#define N_EDGES 800000
#define FDIM 128
#define HIST_BLOCKS 3125   // 800000/256 exactly
#define XW_BLOCKS 391      // ceil(50000/128): 4 waves/block, 32 rows/wave
#define SCAN_BLOCKS 196    // ceil(50000/256) — proven co-resident group

typedef unsigned int uint32;
typedef __attribute__((ext_vector_type(8))) __bf16 bf16x8;
typedef __attribute__((ext_vector_type(8))) short short8;
typedef __attribute__((ext_vector_type(16))) float f32x16;

// sync[] ints: [0] bar1, [1] bar2 (==196 signals scan done), [3] scatter-done
//              [8..8+196) block sums; [208..208+196) scanned exclusive bases
#define BAR1 0
#define BAR2 1
#define DONE 3
#define SUMS 8
#define SCANNED 208

// round-to-nearest-even fp32 -> bf16 bits (finite inputs)
__device__ inline unsigned short f2bf(float f) {
  unsigned int u = __float_as_uint(f);
  unsigned int r = u + 0x7fffu + ((u >> 16) & 1u);
  return (unsigned short)(r >> 16);
}

// ---------------------------------------------------------------------------
// D1: GRU-evolve W -> bf16 frag-blocked Wb (global), + zero cnt/sync.
// Wb[((k>>3)<<7 | n)<<3 | (k&7)] = bf16(W[k][n]): one B-fragment (8
// consecutive k, fixed n) = one 16-B load, L1/L2-hot for the xw waves.
// ---------------------------------------------------------------------------
__global__ __launch_bounds__(256) void evolve_kernel(
    const float* __restrict__ W0, const float* __restrict__ Wih,
    const float* __restrict__ Whh, const float* __restrict__ bih,
    const float* __restrict__ bhh, unsigned short* __restrict__ Wb,
    int* __restrict__ cnt, int* __restrict__ sync) {
  int bid = blockIdx.x;  // 0..127 = W row (contraction index k)
  int t = threadIdx.x;
  // fused init: zero cnt[0..N_NODES) and sync counters
  int gid = bid * 256 + t;  // 0..32767
  for (int j = gid; j < N_NODES; j += 128 * 256) cnt[j] = 0;
  if (gid < 8) sync[gid] = 0;

  __shared__ float w0s[FDIM];
  __shared__ float gis[3 * FDIM];
  __shared__ float ghs[3 * FDIM];
  if (t < FDIM) w0s[t] = W0[bid * FDIM + t];
  __syncthreads();
  for (int jj = t; jj < 3 * FDIM; jj += 256) {
    float gi = bih[jj], gh = bhh[jj];
    const float4* wih4 = (const float4*)(Wih + jj * FDIM);
    const float4* whh4 = (const float4*)(Whh + jj * FDIM);
#pragma unroll 8
    for (int k = 0; k < FDIM / 4; k++) {
      float4 a = wih4[k];
      float4 b = whh4[k];
      float w0a = w0s[4 * k], w0b = w0s[4 * k + 1];
      float w0c = w0s[4 * k + 2], w0d = w0s[4 * k + 3];
      gi += a.x * w0a + a.y * w0b + a.z * w0c + a.w * w0d;
      gh += b.x * w0a + b.y * w0b + b.z * w0c + b.w * w0d;
    }
    gis[jj] = gi;
    ghs[jj] = gh;
  }
  __syncthreads();
  if (t < FDIM) {
    float r = 1.0f / (1.0f + expf(-(gis[t] + ghs[t])));
    float z = 1.0f / (1.0f + expf(-(gis[t + FDIM] + ghs[t + FDIM])));
    float nn = tanhf(gis[t + 2 * FDIM] + r * ghs[t + 2 * FDIM]);
    float w = (1.0f - z) * nn + z * w0s[t];
    Wb[((((bid >> 3) << 7) | t) << 3) | (bid & 7)] = f2bf(w);
  }
}

// ---------------------------------------------------------------------------
// D2 (no LDS, no spins): blocks [0,HIST_BLOCKS) rank histogram (1 atomic per
// edge, launch first); blocks [HIST_BLOCKS..) MFMA y = bf16(x @ W), B-frags
// read straight from global Wb.
// ---------------------------------------------------------------------------
__global__ void histxw_kernel(const int* __restrict__ ei,
                              int* __restrict__ cnt, int* __restrict__ rank,
                              const float* __restrict__ x,
                              const unsigned short* __restrict__ Wb,
                              unsigned short* __restrict__ y, int n) {
  int t = threadIdx.x;
  int bid = blockIdx.x;
  if (bid < HIST_BLOCKS) {
    int idx = bid * 256 + t;  // 3125*256 == 800000 exactly
    int dst = ei[N_EDGES + idx];
    rank[idx] = atomicAdd(&cnt[dst], 1);
    return;
  }
  // ---- xw path: one wave per 32-row tile, 32x32x16 bf16 MFMA ----
  int lane = t & 63;
  int wid = (bid - HIST_BLOCKS) * 4 + (t >> 6);
  int tr = wid * 32;
  if (tr >= n) return;
  int m = lane & 31;   // A row / D col within tile
  int q2 = lane >> 5;  // half-wave: k-offset selector

  int row = tr + m;
  if (row >= n) row = n - 1;  // tail clamp (stores are guarded)
  const float* xr = x + (size_t)row * FDIM;

  bf16x8 a[8];
#pragma unroll
  for (int kc = 0; kc < 8; kc++) {
    int k0 = kc * 16 + q2 * 8;
    float4 p = *(const float4*)(xr + k0);
    float4 q = *(const float4*)(xr + k0 + 4);
    short8 s;
    s[0] = (short)f2bf(p.x); s[1] = (short)f2bf(p.y);
    s[2] = (short)f2bf(p.z); s[3] = (short)f2bf(p.w);
    s[4] = (short)f2bf(q.x); s[5] = (short)f2bf(q.y);
    s[6] = (short)f2bf(q.z); s[7] = (short)f2bf(q.w);
    a[kc] = __builtin_bit_cast(bf16x8, s);
  }

  f32x16 acc[4];
#pragma unroll
  for (int ct = 0; ct < 4; ct++) {
#pragma unroll
    for (int r = 0; r < 16; r++) acc[ct][r] = 0.0f;
  }
#pragma unroll
  for (int ct = 0; ct < 4; ct++) {
    int nn = ct * 32 + m;
#pragma unroll
    for (int kc = 0; kc < 8; kc++) {
      int kg = kc * 2 + q2;
      bf16x8 b = __builtin_bit_cast(
          bf16x8, *(const short8*)(Wb + (((kg << 7) + nn) << 3)));
      acc[ct] = __builtin_amdgcn_mfma_f32_32x32x16_bf16(a[kc], b, acc[ct], 0,
                                                        0, 0);
    }
  }

  // D layout: col = lane&31, row = (reg&3) + 8*(reg>>2) + 4*(lane>>5)
#pragma unroll
  for (int r = 0; r < 16; r++) {
    int rl = (r & 3) + ((r >> 2) << 3) + (q2 << 2);
    int rg = tr + rl;
    if (rg < n) {
#pragma unroll
      for (int ct = 0; ct < 4; ct++) {
        y[(size_t)rg * FDIM + ct * 32 + m] = f2bf(acc[ct][r]);
      }
    }
  }
}

// barrier among the first SCAN_BLOCKS blocks only (proven co-resident).
__device__ inline void bar196(int* ctr, int t) {
  __syncthreads();
  if (t == 0) {
    __hip_atomic_fetch_add(ctr, 1, __ATOMIC_ACQ_REL, __HIP_MEMORY_SCOPE_AGENT);
    while (__hip_atomic_load(ctr, __ATOMIC_ACQUIRE,
                             __HIP_MEMORY_SCOPE_AGENT) < SCAN_BLOCKS) {
      __builtin_amdgcn_s_sleep(1);
    }
  }
  __syncthreads();
}

// ---------------------------------------------------------------------------
// D3 (3125 blocks): scan (blocks 0..195 w/ internal 196-barrier) ->
// scatter (all blocks, 1 edge/thread; blocks 196+ spin on the bar2 counter,
// which is set by LOWER-id blocks -> deadlock-free) -> deg/dinv (blocks
// 0..195 spin on a done counter; they hold only 196 slots so the other 2929
// blocks drain freely).
// ---------------------------------------------------------------------------
__global__ __launch_bounds__(256) void mega3_kernel(
    const int* __restrict__ ei, const float* __restrict__ ew,
    const int* __restrict__ cnt, const int* __restrict__ rank,
    int* __restrict__ sync, int* __restrict__ lexcl, int* __restrict__ offs,
    int2* csr, float* __restrict__ dinv, int n) {
  __shared__ int tmp[256];
  int t = threadIdx.x, bid = blockIdx.x;
  int idx = bid * 256 + t;

  if (bid < SCAN_BLOCKS) {
    // P1: local exclusive scan of cnt
    int v = (idx < n) ? cnt[idx] : 0;
    tmp[t] = v;
    __syncthreads();
#pragma unroll
    for (int off = 1; off < 256; off <<= 1) {
      int u = (t >= off) ? tmp[t - off] : 0;
      __syncthreads();
      tmp[t] += u;
      __syncthreads();
    }
    if (idx < n) lexcl[idx] = tmp[t] - v;
    if (t == 255) sync[SUMS + bid] = tmp[255];
    bar196(&sync[BAR1], t);
    // P2: block 0 scans the 196 partials
    if (bid == 0) {
      int pv = (t < SCAN_BLOCKS) ? sync[SUMS + t] : 0;
      tmp[t] = pv;
      __syncthreads();
#pragma unroll
      for (int off = 1; off < 256; off <<= 1) {
        int u = (t >= off) ? tmp[t - off] : 0;
        __syncthreads();
        tmp[t] += u;
        __syncthreads();
      }
      if (t < SCAN_BLOCKS) sync[SCANNED + t] = tmp[t] - pv;
      if (t == SCAN_BLOCKS - 1) offs[n] = tmp[t];  // = N_EDGES
    }
    bar196(&sync[BAR2], t);  // counter hits 196 => scan results published
    // write this block's offs tile
    if (idx < n) offs[idx] = sync[SCANNED + (idx >> 8)] + lexcl[idx];
  } else {
    // wait for scan completion (lower-ID blocks -> launched first -> safe)
    if (t == 0) {
      while (__hip_atomic_load(&sync[BAR2], __ATOMIC_ACQUIRE,
                               __HIP_MEMORY_SCOPE_AGENT) < SCAN_BLOCKS) {
        __builtin_amdgcn_s_sleep(2);
      }
    }
    __syncthreads();
  }

  // scatter: exactly one edge per thread (3125*256 == 800000)
  {
    int j = idx;
    int src = ei[j];
    int dst = ei[N_EDGES + j];
    int pos = sync[SCANNED + (dst >> 8)] + lexcl[dst] + rank[j];
    csr[pos] = make_int2(src, __float_as_int(ew[j]));
  }
  __threadfence();
  __syncthreads();
  if (t == 0)
    __hip_atomic_fetch_add(&sync[DONE], 1, __ATOMIC_ACQ_REL,
                           __HIP_MEMORY_SCOPE_AGENT);

  // deg/dinv: first 196 blocks wait for all scatters, then 1 node/thread
  if (bid < SCAN_BLOCKS) {
    if (t == 0) {
      while (__hip_atomic_load(&sync[DONE], __ATOMIC_ACQUIRE,
                               __HIP_MEMORY_SCOPE_AGENT) < HIST_BLOCKS) {
        __builtin_amdgcn_s_sleep(2);
      }
    }
    __syncthreads();
    if (idx < n) {
      int b = offs[idx], e = offs[idx + 1];
      float d = 1.0f;
      for (int j = b; j < e; j++) d += __int_as_float(csr[j].y);
      dinv[idx] = (d > 0.0f) ? rsqrtf(d) : 0.0f;
    }
  }
}

// ---------------------------------------------------------------------------
// D4: per-node gather (bf16 y rows) + tanh + w_lin dot + bias.
// h[dst] = tanh( dinv_d * ( dinv_d*y[dst] + sum_e w_e*dinv[src]*y[src] ) )
// ---------------------------------------------------------------------------
__global__ __launch_bounds__(256) void gather_kernel(
    const uint32* __restrict__ yb, const int* __restrict__ offs,
    const int2* __restrict__ csr, const float* __restrict__ dinv,
    const float* __restrict__ wl, const float* __restrict__ bl,
    float* __restrict__ out, int n) {
  int wid = (int)((blockIdx.x * (size_t)blockDim.x + threadIdx.x) >> 6);
  int lane = threadIdx.x & 63;
  if (wid >= n) return;
  float di = dinv[wid];
  uint32 uv = yb[(size_t)wid * 64 + lane];
  float ax = di * __uint_as_float(uv << 16);
  float ay = di * __uint_as_float(uv & 0xffff0000u);
  int beg = offs[wid], end = offs[wid + 1];
  int e = beg;
  for (; e + 8 <= end; e += 8) {
    int2 c[8];
    uint32 u[8];
    float dv[8];
#pragma unroll
    for (int q = 0; q < 8; q++) c[q] = csr[e + q];
#pragma unroll
    for (int q = 0; q < 8; q++) u[q] = yb[(size_t)c[q].x * 64 + lane];
#pragma unroll
    for (int q = 0; q < 8; q++) dv[q] = dinv[c[q].x];
#pragma unroll
    for (int q = 0; q < 8; q++) {
      float wn = __int_as_float(c[q].y) * dv[q];
      ax += wn * __uint_as_float(u[q] << 16);
      ay += wn * __uint_as_float(u[q] & 0xffff0000u);
    }
  }
  for (; e < end; e++) {
    int2 c = csr[e];
    uint32 u = yb[(size_t)c.x * 64 + lane];
    float wn = __int_as_float(c.y) * dinv[c.x];
    ax += wn * __uint_as_float(u << 16);
    ay += wn * __uint_as_float(u & 0xffff0000u);
  }
  float2 wv = ((const float2*)wl)[lane];
  float p = tanhf(di * ax) * wv.x + tanhf(di * ay) * wv.y;
#pragma unroll
  for (int o = 32; o > 0; o >>= 1) p += __shfl_down(p, o, 64);
  if (lane == 0) out[wid] = p + bl[0];
}

// ---------------------------------------------------------------------------
extern "C" void kernel_launch(void* const* d_in, const int* in_sizes, int n_in,
                              void* d_out, int out_size, void* d_ws,
                              size_t ws_size, hipStream_t stream) {
  const float* x = (const float*)d_in[0];     // (N,128)
  const int* ei = (const int*)d_in[1];        // (2,E)
  const float* ew = (const float*)d_in[2];    // (E,)
  const float* W0 = (const float*)d_in[3];    // (128,128)
  const float* Wih = (const float*)d_in[4];   // (384,128)
  const float* Whh = (const float*)d_in[5];   // (384,128)
  const float* bih = (const float*)d_in[6];   // (384,)
  const float* bhh = (const float*)d_in[7];   // (384,)
  const float* wl = (const float*)d_in[8];    // (1,128)
  const float* bl = (const float*)d_in[9];    // (1,)
  float* out = (float*)d_out;                 // (N,1)

  // Workspace layout (16B-aligned)
  unsigned short* Wb = (unsigned short*)d_ws;            // 16384 bf16 (32 KB)
  unsigned short* y = Wb + 16384;                        // N*128 bf16
  float* dinv = (float*)(y + (size_t)N_NODES * FDIM);    // 50000 f
  int* cnt = (int*)(dinv + N_NODES);                     // 50000 i
  int* sync = cnt + N_NODES;                             // 512 i
  int* rank = sync + 512;                                // 800000 i
  int* lexcl = rank + N_EDGES;                           // 50000 i
  int* offs = lexcl + N_NODES;                           // 50008 i (padded)
  int2* csr = (int2*)(offs + 50008);                     // 800000 int2

  // D1: evolve W -> bf16 frag-blocked Wb; zero cnt + sync
  evolve_kernel<<<FDIM, 256, 0, stream>>>(W0, Wih, Whh, bih, bhh, Wb, cnt,
                                          sync);
  // D2: rank histogram (blocks 0..3124) + xw-MFMA (blocks 3125..3515)
  histxw_kernel<<<HIST_BLOCKS + XW_BLOCKS, 256, 0, stream>>>(ei, cnt, rank, x,
                                                             Wb, y, N_NODES);
  // D3: scan + scatter + deg/dinv (single dispatch, safe spin ordering)
  mega3_kernel<<<HIST_BLOCKS, 256, 0, stream>>>(ei, ew, cnt, rank, sync, lexcl,
                                                offs, csr, dinv, N_NODES);
  // D4: fused gather + tanh + linear
  gather_kernel<<<(N_NODES * 64) / 256, 256, 0, stream>>>(
      (const uint32*)y, offs, csr, dinv, wl, bl, out, N_NODES);
}

// Round 10
// 220.925 us; speedup vs baseline: 4.6952x; 3.9873x over previous
//
#include <hip/hip_runtime.h>
#include <hip/hip_bf16.h>
#include <hip/hip_fp16.h>
#include <math.h>

#define N_NODES 50000
#define N_EDGES 800000
#define FDIM 128
#define HIST_BLOCKS 3125   // 800000/256 exactly
#define XW_BLOCKS 391      // ceil(50000/128): 4 waves/block, 32 rows/wave
#define SCAN_BLOCKS 196    // ceil(50000/256) — proven co-resident group

typedef unsigned int uint32;
typedef __attribute__((ext_vector_type(8))) __bf16 bf16x8;
typedef __attribute__((ext_vector_type(8))) short short8;
typedef __attribute__((ext_vector_type(16))) float f32x16;

// sync[] ints: [0]=FLAG_A, [1]=FLAG_B, [8..204) block sums,
//              [208..404) scanned exclusive bases
#define FLAG_A 0
#define FLAG_B 1
#define SUMS 8
#define SCANNED 208

// round-to-nearest-even fp32 -> bf16 bits (finite inputs)
__device__ inline unsigned short f2bf(float f) {
  unsigned int u = __float_as_uint(f);
  unsigned int r = u + 0x7fffu + ((u >> 16) & 1u);
  return (unsigned short)(r >> 16);
}

// ---------------------------------------------------------------------------
// D1: GRU-evolve W -> bf16 frag-blocked Wb (global), + zero cnt/sync flags.
// Wb[((k>>3)<<7 | n)<<3 | (k&7)] = bf16(W[k][n]): one B-fragment (8
// consecutive k, fixed n) = one 16-B load, L1/L2-hot for the xw waves.
// ---------------------------------------------------------------------------
__global__ __launch_bounds__(256) void evolve_kernel(
    const float* __restrict__ W0, const float* __restrict__ Wih,
    const float* __restrict__ Whh, const float* __restrict__ bih,
    const float* __restrict__ bhh, unsigned short* __restrict__ Wb,
    int* __restrict__ cnt, int* __restrict__ sync) {
  int bid = blockIdx.x;  // 0..127 = W row (contraction index k)
  int t = threadIdx.x;
  int gid = bid * 256 + t;  // 0..32767
  for (int j = gid; j < N_NODES; j += 128 * 256) cnt[j] = 0;
  if (gid < 8) sync[gid] = 0;

  __shared__ float w0s[FDIM];
  __shared__ float gis[3 * FDIM];
  __shared__ float ghs[3 * FDIM];
  if (t < FDIM) w0s[t] = W0[bid * FDIM + t];
  __syncthreads();
  for (int jj = t; jj < 3 * FDIM; jj += 256) {
    float gi = bih[jj], gh = bhh[jj];
    const float4* wih4 = (const float4*)(Wih + jj * FDIM);
    const float4* whh4 = (const float4*)(Whh + jj * FDIM);
#pragma unroll 8
    for (int k = 0; k < FDIM / 4; k++) {
      float4 a = wih4[k];
      float4 b = whh4[k];
      float w0a = w0s[4 * k], w0b = w0s[4 * k + 1];
      float w0c = w0s[4 * k + 2], w0d = w0s[4 * k + 3];
      gi += a.x * w0a + a.y * w0b + a.z * w0c + a.w * w0d;
      gh += b.x * w0a + b.y * w0b + b.z * w0c + b.w * w0d;
    }
    gis[jj] = gi;
    ghs[jj] = gh;
  }
  __syncthreads();
  if (t < FDIM) {
    float r = 1.0f / (1.0f + expf(-(gis[t] + ghs[t])));
    float z = 1.0f / (1.0f + expf(-(gis[t + FDIM] + ghs[t + FDIM])));
    float nn = tanhf(gis[t + 2 * FDIM] + r * ghs[t + 2 * FDIM]);
    float w = (1.0f - z) * nn + z * w0s[t];
    Wb[((((bid >> 3) << 7) | t) << 3) | (bid & 7)] = f2bf(w);
  }
}

// ---------------------------------------------------------------------------
// D2 (no LDS, no spins): blocks [0,HIST_BLOCKS) rank histogram (1 atomic per
// edge, launch first); blocks [HIST_BLOCKS..) MFMA y = bf16(x @ W), B-frags
// read straight from global Wb (L1-hot 32 KB).
// ---------------------------------------------------------------------------
__global__ void histxw_kernel(const int* __restrict__ ei,
                              int* __restrict__ cnt, int* __restrict__ rank,
                              const float* __restrict__ x,
                              const unsigned short* __restrict__ Wb,
                              unsigned short* __restrict__ y, int n) {
  int t = threadIdx.x;
  int bid = blockIdx.x;
  if (bid < HIST_BLOCKS) {
    int idx = bid * 256 + t;  // 3125*256 == 800000 exactly
    int dst = ei[N_EDGES + idx];
    rank[idx] = atomicAdd(&cnt[dst], 1);
    return;
  }
  // ---- xw path: one wave per 32-row tile, 32x32x16 bf16 MFMA ----
  int lane = t & 63;
  int wid = (bid - HIST_BLOCKS) * 4 + (t >> 6);
  int tr = wid * 32;
  if (tr >= n) return;
  int m = lane & 31;   // A row / D col within tile
  int q2 = lane >> 5;  // half-wave: k-offset selector

  int row = tr + m;
  if (row >= n) row = n - 1;  // tail clamp (stores are guarded)
  const float* xr = x + (size_t)row * FDIM;

  bf16x8 a[8];
#pragma unroll
  for (int kc = 0; kc < 8; kc++) {
    int k0 = kc * 16 + q2 * 8;
    float4 p = *(const float4*)(xr + k0);
    float4 q = *(const float4*)(xr + k0 + 4);
    short8 s;
    s[0] = (short)f2bf(p.x); s[1] = (short)f2bf(p.y);
    s[2] = (short)f2bf(p.z); s[3] = (short)f2bf(p.w);
    s[4] = (short)f2bf(q.x); s[5] = (short)f2bf(q.y);
    s[6] = (short)f2bf(q.z); s[7] = (short)f2bf(q.w);
    a[kc] = __builtin_bit_cast(bf16x8, s);
  }

  f32x16 acc[4];
#pragma unroll
  for (int ct = 0; ct < 4; ct++) {
#pragma unroll
    for (int r = 0; r < 16; r++) acc[ct][r] = 0.0f;
  }
#pragma unroll
  for (int ct = 0; ct < 4; ct++) {
    int nn = ct * 32 + m;
#pragma unroll
    for (int kc = 0; kc < 8; kc++) {
      int kg = kc * 2 + q2;
      bf16x8 b = __builtin_bit_cast(
          bf16x8, *(const short8*)(Wb + (((kg << 7) + nn) << 3)));
      acc[ct] = __builtin_amdgcn_mfma_f32_32x32x16_bf16(a[kc], b, acc[ct], 0,
                                                        0, 0);
    }
  }

  // D layout: col = lane&31, row = (reg&3) + 8*(reg>>2) + 4*(lane>>5)
#pragma unroll
  for (int r = 0; r < 16; r++) {
    int rl = (r & 3) + ((r >> 2) << 3) + (q2 << 2);
    int rg = tr + rl;
    if (rg < n) {
#pragma unroll
      for (int ct = 0; ct < 4; ct++) {
        y[(size_t)rg * FDIM + ct * 32 + m] = f2bf(acc[ct][r]);
      }
    }
  }
}

// ---------------------------------------------------------------------------
// D3: single-dispatch device-wide exclusive scan of cnt -> offs.
// 196 blocks x 256 — all co-resident; spins only within this cohort
// (proven safe: round 6 ran this at full speed).
// ---------------------------------------------------------------------------
__global__ __launch_bounds__(256) void scan_all_kernel(
    const int* __restrict__ cnt, int* __restrict__ sync, int* __restrict__ offs,
    int n) {
  __shared__ int tmp[256];
  int t = threadIdx.x;
  int bid = blockIdx.x;
  int idx = bid * 256 + t;
  int v = (idx < n) ? cnt[idx] : 0;
  tmp[t] = v;
  __syncthreads();
#pragma unroll
  for (int off = 1; off < 256; off <<= 1) {
    int u = (t >= off) ? tmp[t - off] : 0;
    __syncthreads();
    tmp[t] += u;
    __syncthreads();
  }
  int local_excl = tmp[t] - v;
  int block_sum = tmp[255];
  if (t == 0) {
    __hip_atomic_store(&sync[SUMS + bid], block_sum, __ATOMIC_RELEASE,
                       __HIP_MEMORY_SCOPE_AGENT);
    __hip_atomic_fetch_add(&sync[FLAG_A], 1, __ATOMIC_ACQ_REL,
                           __HIP_MEMORY_SCOPE_AGENT);
  }
  if (bid == 0) {
    if (t == 0) {
      while (__hip_atomic_load(&sync[FLAG_A], __ATOMIC_ACQUIRE,
                               __HIP_MEMORY_SCOPE_AGENT) < SCAN_BLOCKS) {
        __builtin_amdgcn_s_sleep(1);
      }
    }
    __syncthreads();
    __shared__ int ps[256];
    int pv = (t < SCAN_BLOCKS)
                 ? __hip_atomic_load(&sync[SUMS + t], __ATOMIC_RELAXED,
                                     __HIP_MEMORY_SCOPE_AGENT)
                 : 0;
    ps[t] = pv;
    __syncthreads();
#pragma unroll
    for (int off = 1; off < 256; off <<= 1) {
      int u = (t >= off) ? ps[t - off] : 0;
      __syncthreads();
      ps[t] += u;
      __syncthreads();
    }
    if (t < SCAN_BLOCKS)
      __hip_atomic_store(&sync[SCANNED + t], ps[t] - pv, __ATOMIC_RELAXED,
                         __HIP_MEMORY_SCOPE_AGENT);
    __syncthreads();
    if (t == 0)
      __hip_atomic_store(&sync[FLAG_B], 1, __ATOMIC_RELEASE,
                         __HIP_MEMORY_SCOPE_AGENT);
  }
  if (t == 0) {
    while (__hip_atomic_load(&sync[FLAG_B], __ATOMIC_ACQUIRE,
                             __HIP_MEMORY_SCOPE_AGENT) == 0) {
      __builtin_amdgcn_s_sleep(1);
    }
  }
  __syncthreads();
  int base = __hip_atomic_load(&sync[SCANNED + bid], __ATOMIC_RELAXED,
                               __HIP_MEMORY_SCOPE_AGENT);
  int excl = base + local_excl;
  if (idx < n) offs[idx] = excl;
  if (idx == n - 1) offs[n] = excl + v;
}

// ---------------------------------------------------------------------------
// D4: scatter edges into 4-byte packed CSR (no atomics).
// entry = (fp16(ew) << 16) | src   [src < 50000 < 2^16]
// ---------------------------------------------------------------------------
__global__ void scatter_kernel(const int* __restrict__ ei,
                               const float* __restrict__ ew,
                               const int* __restrict__ offs,
                               const int* __restrict__ rank,
                               uint32* __restrict__ csr, int e) {
  int idx = blockIdx.x * blockDim.x + threadIdx.x;
  if (idx < e) {
    int src = ei[idx];
    int dst = ei[N_EDGES + idx];
    unsigned short h = __half_as_ushort(__float2half(ew[idx]));
    csr[offs[dst] + rank[idx]] = ((uint32)h << 16) | (uint32)src;
  }
}

// ---------------------------------------------------------------------------
// D5: deg from packed CSR (atomic-free) -> dinv. One thread per node.
// ---------------------------------------------------------------------------
__global__ __launch_bounds__(256) void deg_dinv_kernel(
    const uint32* __restrict__ csr, const int* __restrict__ offs,
    float* __restrict__ dinv, int n) {
  int i = blockIdx.x * blockDim.x + threadIdx.x;
  if (i >= n) return;
  int b = offs[i], e = offs[i + 1];
  float d = 1.0f;
  for (int j = b; j < e; j++)
    d += __half2float(__ushort_as_half((unsigned short)(csr[j] >> 16)));
  dinv[i] = rsqrtf(d);  // d >= 1 always
}

// ---------------------------------------------------------------------------
// D6: per-node gather (bf16 y rows) + tanh + w_lin dot + bias.
// h[dst] = tanh( dinv_d * ( dinv_d*y[dst] + sum_e ew_e*dinv_s*y[src] ) )
// ---------------------------------------------------------------------------
__global__ __launch_bounds__(256) void gather_kernel(
    const uint32* __restrict__ yb, const int* __restrict__ offs,
    const uint32* __restrict__ csr, const float* __restrict__ dinv,
    const float* __restrict__ wl, const float* __restrict__ bl,
    float* __restrict__ out, int n) {
  int wid = (int)((blockIdx.x * (size_t)blockDim.x + threadIdx.x) >> 6);
  int lane = threadIdx.x & 63;
  if (wid >= n) return;
  float di = dinv[wid];
  uint32 uv = yb[(size_t)wid * 64 + lane];
  float ax = di * __uint_as_float(uv << 16);
  float ay = di * __uint_as_float(uv & 0xffff0000u);
  int beg = offs[wid], end = offs[wid + 1];
  int e = beg;
  for (; e + 8 <= end; e += 8) {
    uint32 c[8];
    uint32 u[8];
    float dv[8];
#pragma unroll
    for (int q = 0; q < 8; q++) c[q] = csr[e + q];
#pragma unroll
    for (int q = 0; q < 8; q++) u[q] = yb[(size_t)(c[q] & 0xffffu) * 64 + lane];
#pragma unroll
    for (int q = 0; q < 8; q++) dv[q] = dinv[c[q] & 0xffffu];
#pragma unroll
    for (int q = 0; q < 8; q++) {
      float wn =
          __half2float(__ushort_as_half((unsigned short)(c[q] >> 16))) * dv[q];
      ax += wn * __uint_as_float(u[q] << 16);
      ay += wn * __uint_as_float(u[q] & 0xffff0000u);
    }
  }
  for (; e < end; e++) {
    uint32 c = csr[e];
    uint32 u = yb[(size_t)(c & 0xffffu) * 64 + lane];
    float wn = __half2float(__ushort_as_half((unsigned short)(c >> 16))) *
               dinv[c & 0xffffu];
    ax += wn * __uint_as_float(u << 16);
    ay += wn * __uint_as_float(u & 0xffff0000u);
  }
  float2 wv = ((const float2*)wl)[lane];
  float p = tanhf(di * ax) * wv.x + tanhf(di * ay) * wv.y;
#pragma unroll
  for (int o = 32; o > 0; o >>= 1) p += __shfl_down(p, o, 64);
  if (lane == 0) out[wid] = p + bl[0];
}

// ---------------------------------------------------------------------------
extern "C" void kernel_launch(void* const* d_in, const int* in_sizes, int n_in,
                              void* d_out, int out_size, void* d_ws,
                              size_t ws_size, hipStream_t stream) {
  const float* x = (const float*)d_in[0];     // (N,128)
  const int* ei = (const int*)d_in[1];        // (2,E)
  const float* ew = (const float*)d_in[2];    // (E,)
  const float* W0 = (const float*)d_in[3];    // (128,128)
  const float* Wih = (const float*)d_in[4];   // (384,128)
  const float* Whh = (const float*)d_in[5];   // (384,128)
  const float* bih = (const float*)d_in[6];   // (384,)
  const float* bhh = (const float*)d_in[7];   // (384,)
  const float* wl = (const float*)d_in[8];    // (1,128)
  const float* bl = (const float*)d_in[9];    // (1,)
  float* out = (float*)d_out;                 // (N,1)

  // Workspace layout (16B-aligned)
  unsigned short* Wb = (unsigned short*)d_ws;            // 16384 bf16 (32 KB)
  unsigned short* y = Wb + 16384;                        // N*128 bf16
  float* dinv = (float*)(y + (size_t)N_NODES * FDIM);    // 50000 f
  int* cnt = (int*)(dinv + N_NODES);                     // 50000 i
  int* sync = cnt + N_NODES;                             // 512 i
  int* rank = sync + 512;                                // 800000 i
  int* offs = rank + N_EDGES;                            // 50008 i (padded)
  uint32* csr = (uint32*)(offs + 50008);                 // 800000 u32

  // D1: evolve W -> bf16 frag-blocked Wb; zero cnt + sync flags
  evolve_kernel<<<FDIM, 256, 0, stream>>>(W0, Wih, Whh, bih, bhh, Wb, cnt,
                                          sync);
  // D2: rank histogram (blocks 0..3124) + xw-MFMA (blocks 3125..3515)
  histxw_kernel<<<HIST_BLOCKS + XW_BLOCKS, 256, 0, stream>>>(ei, cnt, rank, x,
                                                             Wb, y, N_NODES);
  // D3: 196-block co-resident scan -> offs
  scan_all_kernel<<<SCAN_BLOCKS, 256, 0, stream>>>(cnt, sync, offs, N_NODES);
  // D4: scatter to packed CSR (no atomics)
  scatter_kernel<<<HIST_BLOCKS, 256, 0, stream>>>(ei, ew, offs, rank, csr,
                                                  N_EDGES);
  // D5: deg from CSR -> dinv
  deg_dinv_kernel<<<SCAN_BLOCKS, 256, 0, stream>>>(csr, offs, dinv, N_NODES);
  // D6: fused gather + tanh + linear
  gather_kernel<<<(N_NODES * 64) / 256, 256, 0, stream>>>(
      (const uint32*)y, offs, csr, dinv, wl, bl, out, N_NODES);
}

// Round 11
// 219.527 us; speedup vs baseline: 4.7251x; 1.0064x over previous
//
#include <hip/hip_runtime.h>
#include <hip/hip_bf16.h>
#include <hip/hip_fp16.h>
#include <math.h>

#define N_NODES 50000
#define N_EDGES 800000
#define FDIM 128
#define HIST_BLOCKS 782    // ceil(800000 / (256*4)) grid-stride, 4 edges/thread
#define HIST_STRIDE (HIST_BLOCKS * 256)  // 200192
#define XW_BLOCKS 391      // ceil(50000/128): 4 waves/block, 32 rows/wave
#define SCAN_BLOCKS 196    // ceil(50000/256) — proven co-resident group
#define FIX_SCALE 1048576.0f       // 2^20 fixed-point for degree accumulation
#define FIX_INV (1.0f / 1048576.0f)

typedef unsigned int uint32;
typedef unsigned long long uint64;
typedef __attribute__((ext_vector_type(8))) __bf16 bf16x8;
typedef __attribute__((ext_vector_type(8))) short short8;
typedef __attribute__((ext_vector_type(16))) float f32x16;

// sync[] ints: [0]=FLAG_A, [1]=FLAG_B, [8..204) block sums,
//              [208..404) scanned exclusive bases
#define FLAG_A 0
#define FLAG_B 1
#define SUMS 8
#define SCANNED 208

// round-to-nearest-even fp32 -> bf16 bits (finite inputs)
__device__ inline unsigned short f2bf(float f) {
  unsigned int u = __float_as_uint(f);
  unsigned int r = u + 0x7fffu + ((u >> 16) & 1u);
  return (unsigned short)(r >> 16);
}

// ---------------------------------------------------------------------------
// D1: GRU-evolve W -> bf16 frag-blocked Wb (global), + zero cnt64/sync.
// Wb[((k>>3)<<7 | n)<<3 | (k&7)] = bf16(W[k][n]): one B-fragment (8
// consecutive k, fixed n) = one 16-B load, L1/L2-hot for the xw waves.
// ---------------------------------------------------------------------------
__global__ __launch_bounds__(256) void evolve_kernel(
    const float* __restrict__ W0, const float* __restrict__ Wih,
    const float* __restrict__ Whh, const float* __restrict__ bih,
    const float* __restrict__ bhh, unsigned short* __restrict__ Wb,
    int* __restrict__ cnt64i, int* __restrict__ sync) {
  int bid = blockIdx.x;  // 0..127 = W row (contraction index k)
  int t = threadIdx.x;
  int gid = bid * 256 + t;  // 0..32767
  for (int j = gid; j < 2 * N_NODES; j += 128 * 256) cnt64i[j] = 0;
  if (gid < 8) sync[gid] = 0;

  __shared__ float w0s[FDIM];
  __shared__ float gis[3 * FDIM];
  __shared__ float ghs[3 * FDIM];
  if (t < FDIM) w0s[t] = W0[bid * FDIM + t];
  __syncthreads();
  for (int jj = t; jj < 3 * FDIM; jj += 256) {
    float gi = bih[jj], gh = bhh[jj];
    const float4* wih4 = (const float4*)(Wih + jj * FDIM);
    const float4* whh4 = (const float4*)(Whh + jj * FDIM);
#pragma unroll 8
    for (int k = 0; k < FDIM / 4; k++) {
      float4 a = wih4[k];
      float4 b = whh4[k];
      float w0a = w0s[4 * k], w0b = w0s[4 * k + 1];
      float w0c = w0s[4 * k + 2], w0d = w0s[4 * k + 3];
      gi += a.x * w0a + a.y * w0b + a.z * w0c + a.w * w0d;
      gh += b.x * w0a + b.y * w0b + b.z * w0c + b.w * w0d;
    }
    gis[jj] = gi;
    ghs[jj] = gh;
  }
  __syncthreads();
  if (t < FDIM) {
    float r = 1.0f / (1.0f + expf(-(gis[t] + ghs[t])));
    float z = 1.0f / (1.0f + expf(-(gis[t + FDIM] + ghs[t + FDIM])));
    float nn = tanhf(gis[t + 2 * FDIM] + r * ghs[t + 2 * FDIM]);
    float w = (1.0f - z) * nn + z * w0s[t];
    Wb[((((bid >> 3) << 7) | t) << 3) | (bid & 7)] = f2bf(w);
  }
}

// ---------------------------------------------------------------------------
// D2 (no LDS, no spins): blocks [0,HIST_BLOCKS) run the fused 64-bit
// histogram: one atomicAdd per edge on cnt64[dst] with operand
// (1<<32 | round(ew*2^20)) — high word returns the edge's rank, low word
// accumulates the fixed-point weighted degree. 4 edges/thread, grid-stride.
// Blocks [HIST_BLOCKS..): MFMA y = bf16(x @ W), B-frags from global Wb.
// ---------------------------------------------------------------------------
__global__ void histxw_kernel(const int* __restrict__ ei,
                              const float* __restrict__ ew,
                              uint64* __restrict__ cnt64,
                              int* __restrict__ rank,
                              const float* __restrict__ x,
                              const unsigned short* __restrict__ Wb,
                              unsigned short* __restrict__ y, int n) {
  int t = threadIdx.x;
  int bid = blockIdx.x;
  if (bid < HIST_BLOCKS) {
    int gid = bid * 256 + t;
    int j0 = gid, j1 = gid + HIST_STRIDE, j2 = gid + 2 * HIST_STRIDE,
        j3 = gid + 3 * HIST_STRIDE;
    // gather inputs first (independent loads in flight)
    int d0 = ei[N_EDGES + j0];
    float w0 = ew[j0];
    int d1 = (j1 < N_EDGES) ? ei[N_EDGES + j1] : 0;
    float w1 = (j1 < N_EDGES) ? ew[j1] : 0.0f;
    int d2 = (j2 < N_EDGES) ? ei[N_EDGES + j2] : 0;
    float w2 = (j2 < N_EDGES) ? ew[j2] : 0.0f;
    int d3 = (j3 < N_EDGES) ? ei[N_EDGES + j3] : 0;
    float w3 = (j3 < N_EDGES) ? ew[j3] : 0.0f;
    uint64 i0 = (1ull << 32) | (uint64)__float2uint_rn(w0 * FIX_SCALE);
    uint64 i1 = (1ull << 32) | (uint64)__float2uint_rn(w1 * FIX_SCALE);
    uint64 i2 = (1ull << 32) | (uint64)__float2uint_rn(w2 * FIX_SCALE);
    uint64 i3 = (1ull << 32) | (uint64)__float2uint_rn(w3 * FIX_SCALE);
    uint64 r0 = atomicAdd(&cnt64[d0], i0);
    uint64 r1 = (j1 < N_EDGES) ? atomicAdd(&cnt64[d1], i1) : 0;
    uint64 r2 = (j2 < N_EDGES) ? atomicAdd(&cnt64[d2], i2) : 0;
    uint64 r3 = (j3 < N_EDGES) ? atomicAdd(&cnt64[d3], i3) : 0;
    rank[j0] = (int)(r0 >> 32);
    if (j1 < N_EDGES) rank[j1] = (int)(r1 >> 32);
    if (j2 < N_EDGES) rank[j2] = (int)(r2 >> 32);
    if (j3 < N_EDGES) rank[j3] = (int)(r3 >> 32);
    return;
  }
  // ---- xw path: one wave per 32-row tile, 32x32x16 bf16 MFMA ----
  int lane = t & 63;
  int wid = (bid - HIST_BLOCKS) * 4 + (t >> 6);
  int tr = wid * 32;
  if (tr >= n) return;
  int m = lane & 31;   // A row / D col within tile
  int q2 = lane >> 5;  // half-wave: k-offset selector

  int row = tr + m;
  if (row >= n) row = n - 1;  // tail clamp (stores are guarded)
  const float* xr = x + (size_t)row * FDIM;

  bf16x8 a[8];
#pragma unroll
  for (int kc = 0; kc < 8; kc++) {
    int k0 = kc * 16 + q2 * 8;
    float4 p = *(const float4*)(xr + k0);
    float4 q = *(const float4*)(xr + k0 + 4);
    short8 s;
    s[0] = (short)f2bf(p.x); s[1] = (short)f2bf(p.y);
    s[2] = (short)f2bf(p.z); s[3] = (short)f2bf(p.w);
    s[4] = (short)f2bf(q.x); s[5] = (short)f2bf(q.y);
    s[6] = (short)f2bf(q.z); s[7] = (short)f2bf(q.w);
    a[kc] = __builtin_bit_cast(bf16x8, s);
  }

  f32x16 acc[4];
#pragma unroll
  for (int ct = 0; ct < 4; ct++) {
#pragma unroll
    for (int r = 0; r < 16; r++) acc[ct][r] = 0.0f;
  }
#pragma unroll
  for (int ct = 0; ct < 4; ct++) {
    int nn = ct * 32 + m;
#pragma unroll
    for (int kc = 0; kc < 8; kc++) {
      int kg = kc * 2 + q2;
      bf16x8 b = __builtin_bit_cast(
          bf16x8, *(const short8*)(Wb + (((kg << 7) + nn) << 3)));
      acc[ct] = __builtin_amdgcn_mfma_f32_32x32x16_bf16(a[kc], b, acc[ct], 0,
                                                        0, 0);
    }
  }

  // D layout: col = lane&31, row = (reg&3) + 8*(reg>>2) + 4*(lane>>5)
#pragma unroll
  for (int r = 0; r < 16; r++) {
    int rl = (r & 3) + ((r >> 2) << 3) + (q2 << 2);
    int rg = tr + rl;
    if (rg < n) {
#pragma unroll
      for (int ct = 0; ct < 4; ct++) {
        y[(size_t)rg * FDIM + ct * 32 + m] = f2bf(acc[ct][r]);
      }
    }
  }
}

// ---------------------------------------------------------------------------
// D3: 196-block co-resident exclusive scan of counts -> offs, fused dinv.
// dinv[i] = rsqrt(1 + low32(cnt64[i]) * 2^-20)   (deg >= 1 always)
// ---------------------------------------------------------------------------
__global__ __launch_bounds__(256) void scan_dinv_kernel(
    const uint64* __restrict__ cnt64, int* __restrict__ sync,
    int* __restrict__ offs, float* __restrict__ dinv, int n) {
  __shared__ int tmp[256];
  int t = threadIdx.x;
  int bid = blockIdx.x;
  int idx = bid * 256 + t;
  uint64 cv = (idx < n) ? cnt64[idx] : 0ull;
  int v = (int)(cv >> 32);
  if (idx < n)
    dinv[idx] = rsqrtf(1.0f + (float)(uint32)(cv & 0xffffffffull) * FIX_INV);
  tmp[t] = v;
  __syncthreads();
#pragma unroll
  for (int off = 1; off < 256; off <<= 1) {
    int u = (t >= off) ? tmp[t - off] : 0;
    __syncthreads();
    tmp[t] += u;
    __syncthreads();
  }
  int local_excl = tmp[t] - v;
  int block_sum = tmp[255];
  if (t == 0) {
    __hip_atomic_store(&sync[SUMS + bid], block_sum, __ATOMIC_RELEASE,
                       __HIP_MEMORY_SCOPE_AGENT);
    __hip_atomic_fetch_add(&sync[FLAG_A], 1, __ATOMIC_ACQ_REL,
                           __HIP_MEMORY_SCOPE_AGENT);
  }
  if (bid == 0) {
    if (t == 0) {
      while (__hip_atomic_load(&sync[FLAG_A], __ATOMIC_ACQUIRE,
                               __HIP_MEMORY_SCOPE_AGENT) < SCAN_BLOCKS) {
        __builtin_amdgcn_s_sleep(1);
      }
    }
    __syncthreads();
    __shared__ int ps[256];
    int pv = (t < SCAN_BLOCKS)
                 ? __hip_atomic_load(&sync[SUMS + t], __ATOMIC_RELAXED,
                                     __HIP_MEMORY_SCOPE_AGENT)
                 : 0;
    ps[t] = pv;
    __syncthreads();
#pragma unroll
    for (int off = 1; off < 256; off <<= 1) {
      int u = (t >= off) ? ps[t - off] : 0;
      __syncthreads();
      ps[t] += u;
      __syncthreads();
    }
    if (t < SCAN_BLOCKS)
      __hip_atomic_store(&sync[SCANNED + t], ps[t] - pv, __ATOMIC_RELAXED,
                         __HIP_MEMORY_SCOPE_AGENT);
    __syncthreads();
    if (t == 0)
      __hip_atomic_store(&sync[FLAG_B], 1, __ATOMIC_RELEASE,
                         __HIP_MEMORY_SCOPE_AGENT);
  }
  if (t == 0) {
    while (__hip_atomic_load(&sync[FLAG_B], __ATOMIC_ACQUIRE,
                             __HIP_MEMORY_SCOPE_AGENT) == 0) {
      __builtin_amdgcn_s_sleep(1);
    }
  }
  __syncthreads();
  int base = __hip_atomic_load(&sync[SCANNED + bid], __ATOMIC_RELAXED,
                               __HIP_MEMORY_SCOPE_AGENT);
  int excl = base + local_excl;
  if (idx < n) offs[idx] = excl;
  if (idx == n - 1) offs[n] = excl + v;
}

// ---------------------------------------------------------------------------
// D4: scatter edges into 4-byte packed CSR with FULL norm baked in:
// entry = (fp16(ew * dinv[src] * dinv[dst]) << 16) | src   [src < 2^16]
// ---------------------------------------------------------------------------
__global__ void scatter_kernel(const int* __restrict__ ei,
                               const float* __restrict__ ew,
                               const int* __restrict__ offs,
                               const int* __restrict__ rank,
                               const float* __restrict__ dinv,
                               uint32* __restrict__ csr, int e) {
  int idx = blockIdx.x * blockDim.x + threadIdx.x;
  if (idx < e) {
    int src = ei[idx];
    int dst = ei[N_EDGES + idx];
    float nrm = ew[idx] * dinv[src] * dinv[dst];
    unsigned short h = __half_as_ushort(__float2half(nrm));
    csr[offs[dst] + rank[idx]] = ((uint32)h << 16) | (uint32)src;
  }
}

// ---------------------------------------------------------------------------
// D5: per-node gather (bf16 y rows) + tanh + w_lin dot + bias.
// h[dst] = tanh( dinv_d^2 * y[dst] + sum_e wnorm_e * y[src_e] )
// Inner loop: one 4B csr broadcast + one 4B y load per lane per edge.
// ---------------------------------------------------------------------------
__global__ __launch_bounds__(256) void gather_kernel(
    const uint32* __restrict__ yb, const int* __restrict__ offs,
    const uint32* __restrict__ csr, const float* __restrict__ dinv,
    const float* __restrict__ wl, const float* __restrict__ bl,
    float* __restrict__ out, int n) {
  int wid = (int)((blockIdx.x * (size_t)blockDim.x + threadIdx.x) >> 6);
  int lane = threadIdx.x & 63;
  if (wid >= n) return;
  float di = dinv[wid];
  float sn = di * di;  // self-loop norm
  uint32 uv = yb[(size_t)wid * 64 + lane];
  float ax = sn * __uint_as_float(uv << 16);
  float ay = sn * __uint_as_float(uv & 0xffff0000u);
  int beg = offs[wid], end = offs[wid + 1];
  int e = beg;
  for (; e + 8 <= end; e += 8) {
    uint32 c[8];
    uint32 u[8];
#pragma unroll
    for (int q = 0; q < 8; q++) c[q] = csr[e + q];
#pragma unroll
    for (int q = 0; q < 8; q++) u[q] = yb[(size_t)(c[q] & 0xffffu) * 64 + lane];
#pragma unroll
    for (int q = 0; q < 8; q++) {
      float wn = __half2float(__ushort_as_half((unsigned short)(c[q] >> 16)));
      ax += wn * __uint_as_float(u[q] << 16);
      ay += wn * __uint_as_float(u[q] & 0xffff0000u);
    }
  }
  for (; e < end; e++) {
    uint32 c = csr[e];
    uint32 u = yb[(size_t)(c & 0xffffu) * 64 + lane];
    float wn = __half2float(__ushort_as_half((unsigned short)(c >> 16)));
    ax += wn * __uint_as_float(u << 16);
    ay += wn * __uint_as_float(u & 0xffff0000u);
  }
  float2 wv = ((const float2*)wl)[lane];
  float p = tanhf(ax) * wv.x + tanhf(ay) * wv.y;
#pragma unroll
  for (int o = 32; o > 0; o >>= 1) p += __shfl_down(p, o, 64);
  if (lane == 0) out[wid] = p + bl[0];
}

// ---------------------------------------------------------------------------
extern "C" void kernel_launch(void* const* d_in, const int* in_sizes, int n_in,
                              void* d_out, int out_size, void* d_ws,
                              size_t ws_size, hipStream_t stream) {
  const float* x = (const float*)d_in[0];     // (N,128)
  const int* ei = (const int*)d_in[1];        // (2,E)
  const float* ew = (const float*)d_in[2];    // (E,)
  const float* W0 = (const float*)d_in[3];    // (128,128)
  const float* Wih = (const float*)d_in[4];   // (384,128)
  const float* Whh = (const float*)d_in[5];   // (384,128)
  const float* bih = (const float*)d_in[6];   // (384,)
  const float* bhh = (const float*)d_in[7];   // (384,)
  const float* wl = (const float*)d_in[8];    // (1,128)
  const float* bl = (const float*)d_in[9];    // (1,)
  float* out = (float*)d_out;                 // (N,1)

  // Workspace layout (16B-aligned)
  unsigned short* Wb = (unsigned short*)d_ws;            // 16384 bf16 (32 KB)
  unsigned short* y = Wb + 16384;                        // N*128 bf16 (12.8MB)
  float* dinv = (float*)(y + (size_t)N_NODES * FDIM);    // 50000 f
  uint64* cnt64 = (uint64*)(dinv + N_NODES);             // 50000 u64 (400 KB)
  int* sync = (int*)(cnt64 + N_NODES);                   // 512 i
  int* rank = sync + 512;                                // 800000 i
  int* offs = rank + N_EDGES;                            // 50008 i (padded)
  uint32* csr = (uint32*)(offs + 50008);                 // 800000 u32

  // D1: evolve W -> bf16 frag-blocked Wb; zero cnt64 + sync flags
  evolve_kernel<<<FDIM, 256, 0, stream>>>(W0, Wih, Whh, bih, bhh, Wb,
                                          (int*)cnt64, sync);
  // D2: fused 64-bit histogram (blocks 0..781) + xw-MFMA (blocks 782..1172)
  histxw_kernel<<<HIST_BLOCKS + XW_BLOCKS, 256, 0, stream>>>(
      ei, ew, cnt64, rank, x, Wb, y, N_NODES);
  // D3: 196-block co-resident scan -> offs, fused dinv
  scan_dinv_kernel<<<SCAN_BLOCKS, 256, 0, stream>>>(cnt64, sync, offs, dinv,
                                                    N_NODES);
  // D4: scatter to packed CSR with full norm (no atomics)
  scatter_kernel<<<(N_EDGES + 255) / 256, 256, 0, stream>>>(ei, ew, offs, rank,
                                                            dinv, csr, N_EDGES);
  // D5: fused gather + tanh + linear
  gather_kernel<<<(N_NODES * 64) / 256, 256, 0, stream>>>(
      (const uint32*)y, offs, csr, dinv, wl, bl, out, N_NODES);
}